// Round 3
// baseline (276.563 us; speedup 1.0000x reference)
//
#include <hip/hip_runtime.h>

// HighQualityNSN2NLoss — B=16, H=W=768, fp32, scalar out. x_ip1 unused.
//
// R6 (post-mortem of R5): pass1 is pinned at ~808 GB/s achieved HBM BW in
// BOTH R3 (768 blk) and R5 (1536 blk) — duration == FETCH/808GB/s exactly.
// That's an MLP ceiling: ~2 outstanding loads/wave (issue row y+1, shfl it
// immediately -> vmcnt drains every iteration). More blocks didn't raise
// residency (occupancy 27->32%, VALUBusy flat 35%).
//  - Depth-2 software prefetch queue: iteration k ISSUES row y+3, CONSUMES
//    row y+1 (issued 2 iters ago). Two full row-computes between issue and
//    s_waitcnt. Loop fully unrolled (HSEG const) -> static register slots.
//  - Back to HSEG=12 / 768 blocks (less halo; R5 proved blocks don't help).
//  - fb append counter LDS -> register (wave-uniform via ballot/popcount);
//    removes an LDS read+write + lgkmcnt chain per 64-px group.
//  - Keep: NCOPY=8 hist copies, pass2 512 blocks, 3-kernel structure
//    (launch overhead measured FIXED ~175us; fusion is a non-lever here).

#define HH 768
#define WW 768
#define BB 16
#define HWSZ (HH * WW)
#define NPXD ((double)BB * (double)HWSZ)

#define NB 1024
#define NHIST (2 * NB)
#define NCOPY 8            // global hist copies (power of 2)

#define STRIPS 3           // 256-wide column strips
#define HSEG 12            // rows per wave-job
#define NSEG (HH / HSEG)   // 64
#define NJOBS (STRIPS * NSEG * BB)  // 3072
#define NBLK1 (NJOBS / 4)           // 768 blocks (4 waves each) = 3/CU

#define FBBUF 128          // per-wave fb buffer (expected ~3.4 hits/wave)

__device__ __forceinline__ float wredf(float v) {
#pragma unroll
  for (int o = 32; o > 0; o >>= 1) v += __shfl_down(v, o, 64);
  return v;
}
__device__ __forceinline__ unsigned wredu(unsigned v) {
#pragma unroll
  for (int o = 32; o > 0; o >>= 1) v += __shfl_down(v, o, 64);
  return v;
}

struct Row {
  float f[4];
  float l, r;
};

// Raw (unshuffled) row: the float4 plus the two strip-edge scalars, all
// issued together so they ride the same vmcnt window.
struct RawRow {
  float4 v;
  float eL, eR;
};

__device__ __forceinline__ RawRow issue_row(const float* __restrict__ p,
                                            int y, int xl, int x0, int lane) {
  RawRow r;
  const float* rp = p + (size_t)y * WW;
  r.v = *(const float4*)(rp + xl);
  r.eL = 0.f;
  r.eR = 0.f;
  if (lane == 0 && x0 > 0) r.eL = rp[x0 - 1];
  if (lane == 63 && x0 + 256 < WW) r.eR = rp[x0 + 256];
  return r;
}

__device__ __forceinline__ Row finish_row(const RawRow& rr, bool valid,
                                          int lane) {
  Row r;
  if (!valid) {  // wave-uniform branch (row outside image)
    r.f[0] = r.f[1] = r.f[2] = r.f[3] = 0.f;
    r.l = 0.f;
    r.r = 0.f;
    return r;
  }
  r.f[0] = rr.v.x; r.f[1] = rr.v.y; r.f[2] = rr.v.z; r.f[3] = rr.v.w;
  float left = __shfl_up(rr.v.w, 1, 64);
  float right = __shfl_down(rr.v.x, 1, 64);
  if (lane == 0) left = rr.eL;
  if (lane == 63) right = rr.eR;
  r.l = left;
  r.r = right;
  return r;
}

#define LNB(row, j) ((j) == 0 ? (row).l : (row).f[(j)-1])
#define RNB(row, j) ((j) == 3 ? (row).r : (row).f[(j) + 1])

// accs: 0 rc, 1 sum_xi_body, 2 sum_yp_body, 3 edge_x, 4 edge_y,
//       5 tex, 6 hf, 7 ic, 8 lf, 9 mid, 10 syn
// cnts: 0 body, 1 tex, 2 flat, 3 fb (append counter)

__global__ __launch_bounds__(256) void pass1_kernel(
    const float* __restrict__ yp, const float* __restrict__ xi,
    const float* __restrict__ wt, double* __restrict__ accs,
    unsigned* __restrict__ cnts, unsigned* __restrict__ fb_list, int fb_cap,
    unsigned* __restrict__ hist_final) {
  __shared__ unsigned s_hist[NHIST];
  __shared__ unsigned s_fb[4][FBBUF];
  __shared__ float s_redf[4][8];
  __shared__ unsigned s_redc[4][3];

  const int tid = threadIdx.x;
  const int lane = tid & 63;
  const int wv = tid >> 6;
  const unsigned long long lmask_lt = (1ull << lane) - 1ull;

  for (int i = tid; i < NHIST; i += 256) s_hist[i] = 0u;
  __syncthreads();

  const int job = blockIdx.x * 4 + wv;
  const int st = job % STRIPS;
  const int seg = (job / STRIPS) % NSEG;
  const int b = job / (STRIPS * NSEG);
  const int x0 = st * 256;
  const int y0 = seg * HSEG;
  const int xl = x0 + lane * 4;
  const size_t base = (size_t)b * HWSZ;
  const float* ypb = yp + base;
  const float* xib = xi + base;
  const float* wtb = wt + base;

  float a_rc = 0.f, a_sxi = 0.f, a_syp = 0.f, a_ex = 0.f, a_ey = 0.f;
  float a_tex = 0.f, a_hf = 0.f, a_ic = 0.f;
  unsigned c_body = 0u, c_tex = 0u, c_flat = 0u;
  unsigned fbn = 0u;  // wave-uniform fb count (register, not LDS)

  // ---- prologue: issue 8 row-loads before the first wait ----
  const int ym1 = (y0 > 0) ? y0 - 1 : 0;
  RawRow t0 = issue_row(ypb, ym1, xl, x0, lane);
  RawRow t1 = issue_row(ypb, y0, xl, x0, lane);
  RawRow t2 = issue_row(xib, ym1, xl, x0, lane);
  RawRow t3 = issue_row(xib, y0, xl, x0, lane);

  RawRow pA[2], iA[2];
  float4 wA[2];
  pA[0] = issue_row(ypb, y0 + 1, xl, x0, lane);   // y0+1 < HH always
  iA[0] = issue_row(xib, y0 + 1, xl, x0, lane);
  wA[0] = *(const float4*)(wtb + (size_t)y0 * WW + xl);
  pA[1] = issue_row(ypb, y0 + 2, xl, x0, lane);   // y0+2 < HH always
  iA[1] = issue_row(xib, y0 + 2, xl, x0, lane);
  wA[1] = *(const float4*)(wtb + (size_t)(y0 + 1) * WW + xl);

  Row pm1 = finish_row(t0, y0 > 0, lane);
  Row pc  = finish_row(t1, true, lane);
  Row im1 = finish_row(t2, y0 > 0, lane);
  Row icr = finish_row(t3, true, lane);

#pragma unroll
  for (int k = 0; k < HSEG; k++) {
    const int y = y0 + k;
    const int s2 = k & 1;

    // issue row y+3 (consumed at iter k+2); compile-time pruned at the tail
    RawRow np = {};
    RawRow ni = {};
    float4 nw = {};
    if (k + 3 <= HSEG) {
      const int r = y + 3;
      const int rc = (r < HH) ? r : HH - 1;  // clamp; zeroed at finish
      np = issue_row(ypb, rc, xl, x0, lane);
      ni = issue_row(xib, rc, xl, x0, lane);
    }
    if (k + 2 <= HSEG - 1) {
      nw = *(const float4*)(wtb + (size_t)(y + 2) * WW + xl);
    }

    // consume row y+1 (issued 2 iterations ago)
    const Row pp1 = finish_row(pA[s2], y + 1 < HH, lane);
    const Row ip1 = finish_row(iA[s2], y + 1 < HH, lane);
    const float4 w4 = wA[s2];
    const float wf[4] = {w4.x, w4.y, w4.z, w4.w};

#pragma unroll
    for (int j = 0; j < 4; j++) {
      const float p00 = LNB(pm1, j), p01 = pm1.f[j], p02 = RNB(pm1, j);
      const float p10 = LNB(pc, j),  p11 = pc.f[j],  p12 = RNB(pc, j);
      const float p20 = LNB(pp1, j), p21 = pp1.f[j], p22 = RNB(pp1, j);
      const float i00 = LNB(im1, j), i01 = im1.f[j], i02 = RNB(im1, j);
      const float i10 = LNB(icr, j), i11 = icr.f[j], i12 = RNB(icr, j);
      const float i20 = LNB(ip1, j), i21 = ip1.f[j], i22 = RNB(ip1, j);

      const float gxp = (p02 - p00) + 2.f * (p12 - p10) + (p22 - p20);
      const float gyp = (p20 - p00) + 2.f * (p21 - p01) + (p22 - p02);
      const float lapp = p01 + p10 + p12 + p21 - 4.f * p11;
      const float gxi_ = (i02 - i00) + 2.f * (i12 - i10) + (i22 - i20);
      const float gyi_ = (i20 - i00) + 2.f * (i21 - i01) + (i22 - i02);
      const float lapi = i01 + i10 + i12 + i21 - 4.f * i11;

      const float yv = p11, xv = i11;
      a_rc += fabsf(yv * wf[j] - xv * wf[j]);

      const bool body = (xv > 0.15f) && (xv < 0.85f);
      if (body) {
        c_body++;
        a_sxi += xv;
        a_syp += yv;
        int bx = (int)(xv * (float)NB);
        bx = bx < 0 ? 0 : (bx > NB - 1 ? NB - 1 : bx);
        int by = (int)(yv * (float)NB);
        by = by < 0 ? 0 : (by > NB - 1 ? NB - 1 : by);
        atomicAdd(&s_hist[bx], 1u);
        atomicAdd(&s_hist[NB + by], 1u);
      }

      a_ex += fabsf(gxp - gxi_);
      a_ey += fabsf(gyp - gyi_);

      const float gmi = sqrtf(gxi_ * gxi_ + gyi_ * gyi_ + 1e-8f);
      const float gmp = sqrtf(gxp * gxp + gyp * gyp + 1e-8f);

      if (gmi > 0.03f && gmi < 0.5f) {
        c_tex++;
        a_tex += fabsf(gmp - gmi);
      }
      const bool flat = gmi < 0.03f;
      if (flat) {
        c_flat++;
        a_hf += fabsf(fabsf(lapp) - 0.3f * fabsf(lapi));
        a_ic += fmaxf(gmp - 2.0f * gmi, 0.f);
      }
      // wave-aggregated append of flat&body pixels
      const bool qual = flat && body;
      const unsigned long long m = __ballot(qual);
      if (m) {
        if (qual) {
          const unsigned p = fbn + (unsigned)__popcll(m & lmask_lt);
          const unsigned gidx = (unsigned)(base + (size_t)y * WW + (xl + j));
          if (p < FBBUF) {
            s_fb[wv][p] = gidx;
          } else {  // overflow fallback (never hit on bench data)
            const unsigned gi = atomicAdd(&cnts[3], 1u);
            if ((int)gi < fb_cap) fb_list[gi] = gidx;
          }
        }
        fbn += (unsigned)__popcll(m);  // wave-uniform
      }
    }

    if (k + 3 <= HSEG) { pA[s2] = np; iA[s2] = ni; }
    if (k + 2 <= HSEG - 1) wA[s2] = nw;
    pm1 = pc; pc = pp1;
    im1 = icr; icr = ip1;
  }

  // flush per-wave fb buffer: ONE global atomic per wave
  {
    unsigned n = fbn;
    if (n > FBBUF) n = FBBUF;
    unsigned gbase = 0u;
    if (lane == 0 && n > 0) gbase = atomicAdd(&cnts[3], n);
    gbase = __shfl(gbase, 0, 64);
    for (unsigned i = lane; i < n; i += 64) {
      const unsigned gi = gbase + i;
      if ((int)gi < fb_cap) fb_list[gi] = s_fb[wv][i];
    }
  }

  __syncthreads();
  // flush block histogram into one of NCOPY global copies (per-bin atomic
  // depth NBLK1/NCOPY = 96; finalize sums the copies)
  {
    const unsigned hco = ((unsigned)blockIdx.x & (NCOPY - 1)) * NHIST;
    for (int i = tid; i < NHIST; i += 256) {
      const unsigned v = s_hist[i];
      if (v) atomicAdd(&hist_final[hco + i], v);
    }
  }

  float f0 = wredf(a_rc), f1 = wredf(a_sxi), f2 = wredf(a_syp);
  float f3 = wredf(a_ex), f4 = wredf(a_ey), f5 = wredf(a_tex);
  float f6 = wredf(a_hf), f7 = wredf(a_ic);
  unsigned u0 = wredu(c_body), u1 = wredu(c_tex), u2 = wredu(c_flat);
  if (lane == 0) {
    s_redf[wv][0] = f0; s_redf[wv][1] = f1; s_redf[wv][2] = f2; s_redf[wv][3] = f3;
    s_redf[wv][4] = f4; s_redf[wv][5] = f5; s_redf[wv][6] = f6; s_redf[wv][7] = f7;
    s_redc[wv][0] = u0; s_redc[wv][1] = u1; s_redc[wv][2] = u2;
  }
  __syncthreads();
  if (tid < 8) {
    double sm = (double)s_redf[0][tid] + (double)s_redf[1][tid] +
                (double)s_redf[2][tid] + (double)s_redf[3][tid];
    atomicAdd(&accs[tid], sm);
  } else if (tid < 11) {
    int k = tid - 8;
    unsigned sm = s_redc[0][k] + s_redc[1][k] + s_redc[2][k] + s_redc[3][k];
    atomicAdd(&cnts[k], sm);
  }
}

__global__ __launch_bounds__(256) void pass2_kernel(
    const float* __restrict__ yp, const float* __restrict__ xi,
    const float* __restrict__ xm, const float* __restrict__ npred,
    const float* __restrict__ nsyn, double* __restrict__ accs,
    const unsigned* __restrict__ cnts, const unsigned* __restrict__ fb_list,
    int fb_cap) {
  __shared__ float w3[19];
  __shared__ float w1[7];
  __shared__ double s_red[4][3];
  const int tid = threadIdx.x;
  const int lane = tid & 63;
  const int wv = tid >> 6;

  if (tid == 0) {
    float tmp[19], s = 0.f;
    for (int i = 0; i < 19; i++) {
      float c = (float)(i - 9) / 3.0f;
      tmp[i] = expf(-0.5f * c * c);
      s += tmp[i];
    }
    for (int i = 0; i < 19; i++) w3[i] = tmp[i] / s;
    float tmp1[7], s1 = 0.f;
    for (int i = 0; i < 7; i++) {
      float c = (float)(i - 3);
      tmp1[i] = expf(-0.5f * c * c);
      s1 += tmp1[i];
    }
    for (int i = 0; i < 7; i++) w1[i] = tmp1[i] / s1;
  }
  __syncthreads();

  unsigned nfb = cnts[3];
  if (nfb > (unsigned)fb_cap) nfb = (unsigned)fb_cap;
  const int wid = (int)((blockIdx.x * blockDim.x + tid) >> 6);
  const int nwaves = (int)((gridDim.x * blockDim.x) >> 6);

  double w_lf = 0.0, w_md = 0.0, w_sy = 0.0;  // lane-0 accumulators

  for (int i = wid; i < (int)nfb; i += nwaves) {
    const unsigned px = fb_list[i];
    const int b = (int)(px / (unsigned)HWSZ);
    const int rem = (int)(px % (unsigned)HWSZ);
    const int y = rem / WW;
    const int x = rem % WW;
    const size_t base = (size_t)b * HWSZ;
    const float* xib = xi + base;
    const float* ypb = yp + base;
    const float* xmb = xm + base;

    float npv = 0.f, nsv = 0.f;
    if (lane == 0) { npv = npred[px]; nsv = nsyn[px]; }

    float s_li = 0.f, s_lp = 0.f, s_lm = 0.f;
    float s_gi = 0.f, s_gp = 0.f;
    const bool interior = (y >= 9) && (y < HH - 9) && (x >= 9) && (x < WW - 9);
    if (interior) {
#pragma unroll
      for (int k = 0; k < 6; k++) {
        const int tap = lane + 64 * k;
        if (tap < 361) {
          const int r = tap / 19, c = tap - r * 19;
          const float wgt = w3[r] * w3[c];
          const int o = (y + r - 9) * WW + (x + c - 9);
          s_li += wgt * xib[o];
          s_lp += wgt * ypb[o];
          s_lm += wgt * xmb[o];
        }
      }
      if (lane < 49) {
        const int r = lane / 7, c = lane - r * 7;
        const float wgt = w1[r] * w1[c];
        const int o = (y + r - 3) * WW + (x + c - 3);
        s_gi = wgt * xib[o];
        s_gp = wgt * ypb[o];
      }
    } else {
#pragma unroll
      for (int k = 0; k < 6; k++) {
        const int tap = lane + 64 * k;
        if (tap < 361) {
          const int r = tap / 19, c = tap - r * 19;
          const int gy = y + r - 9, gx = x + c - 9;
          if (gy >= 0 && gy < HH && gx >= 0 && gx < WW) {
            const float wgt = w3[r] * w3[c];
            const int o = gy * WW + gx;
            s_li += wgt * xib[o];
            s_lp += wgt * ypb[o];
            s_lm += wgt * xmb[o];
          }
        }
      }
      if (lane < 49) {
        const int r = lane / 7, c = lane - r * 7;
        const int gy = y + r - 3, gx = x + c - 3;
        if (gy >= 0 && gy < HH && gx >= 0 && gx < WW) {
          const float wgt = w1[r] * w1[c];
          const int o = gy * WW + gx;
          s_gi = wgt * xib[o];
          s_gp = wgt * ypb[o];
        }
      }
    }
    s_li = wredf(s_li);
    s_lp = wredf(s_lp);
    s_lm = wredf(s_lm);
    s_gi = wredf(s_gi);
    s_gp = wredf(s_gp);
    if (lane == 0) {
      const float lf = fabsf((s_lp - s_lm) - 0.3f * (s_li - s_lm));
      const float mi_ = s_gi - s_li, mp_ = s_gp - s_lp;
      const float md = fabsf(fabsf(mp_) - 0.3f * fabsf(mi_));
      w_lf += (double)lf;
      w_md += (double)md;
      w_sy += (double)fabsf(npv - nsv);
    }
  }

  if (lane == 0) {
    s_red[wv][0] = w_lf; s_red[wv][1] = w_md; s_red[wv][2] = w_sy;
  }
  __syncthreads();
  if (tid < 3) {
    const double t = s_red[0][tid] + s_red[1][tid] + s_red[2][tid] + s_red[3][tid];
    if (t != 0.0) atomicAdd(&accs[8 + tid], t);
  }
}

__global__ __launch_bounds__(256) void finalize_kernel(
    const double* __restrict__ accs, const unsigned* __restrict__ cnts,
    const unsigned* __restrict__ hist, float* __restrict__ out) {
  __shared__ unsigned sc[NHIST];
  __shared__ unsigned wsum[8];
  __shared__ double quant[4];
  const int tid = threadIdx.x;
  const int lane = tid & 63;
  const int wv = tid >> 6;

  if (tid < 4) quant[tid] = 0.0;

#pragma unroll
  for (int h = 0; h < 2; h++) {
    const int baseh = h * NB + tid * 4;
    unsigned v0 = 0u, v1 = 0u, v2 = 0u, v3 = 0u;
#pragma unroll
    for (int c = 0; c < NCOPY; c++) {
      const unsigned* hb = hist + c * NHIST + baseh;
      v0 += hb[0];
      v1 += hb[1];
      v2 += hb[2];
      v3 += hb[3];
    }
    const unsigned s = v0 + v1 + v2 + v3;
    unsigned scl = s;
#pragma unroll
    for (int o = 1; o < 64; o <<= 1) {
      const unsigned t = __shfl_up(scl, o, 64);
      if (lane >= o) scl += t;
    }
    if (lane == 63) wsum[h * 4 + wv] = scl;
    __syncthreads();
    unsigned woff = 0;
    for (int k = 0; k < wv; k++) woff += wsum[h * 4 + k];
    const unsigned excl = woff + scl - s;
    const unsigned c0 = excl + v0;
    const unsigned c1 = c0 + v1;
    const unsigned c2 = c1 + v2;
    const unsigned c3 = c2 + v3;
    sc[baseh + 0] = c0;
    sc[baseh + 1] = c1;
    sc[baseh + 2] = c2;
    sc[baseh + 3] = c3;
    __syncthreads();
  }

  const unsigned nb = cnts[0];
  if (tid < 4 && nb > 4096u) {
    const int h = tid >> 1;
    const double q = (tid & 1) ? 0.75 : 0.25;
    const double pos = q * (double)(nb - 1u);
    int lo = 0, hi = NB - 1;
    while (lo < hi) {
      const int mid = (lo + hi) >> 1;
      if ((double)sc[h * NB + mid] > pos) hi = mid; else lo = mid + 1;
    }
    const unsigned cum_before = (lo > 0) ? sc[h * NB + lo - 1] : 0u;
    const unsigned m = sc[h * NB + lo] - cum_before;
    const double local = pos - (double)cum_before;
    quant[tid] = ((double)lo + (local + 0.5) / (double)(m ? m : 1u)) *
                 (1.0 / (double)NB);
  }
  __syncthreads();
  if (tid != 0) return;

  const unsigned ntex = cnts[1], nflat = cnts[2], nfb = cnts[3];
  const double loss_rc = accs[0] / NPXD;
  const double denb = (double)(nb > 0u ? nb : 1u);
  const double mean_in = accs[1] / denb;
  const double mean_pr = accs[2] / denb;

  double loss_hu = 0.0;
  if (nb > 4096u) {
    const double q25i = quant[0], q75i = quant[1];
    const double q25p = quant[2], q75p = quant[3];
    const double d = mean_pr - mean_in;
    loss_hu = d * d + 0.5 * ((q25p - q25i) * (q25p - q25i) +
                             (q75p - q75i) * (q75p - q75i));
  }

  const double loss_edge = accs[3] / NPXD + accs[4] / NPXD;
  const double loss_tex = (ntex > 100u) ? accs[5] / (double)(ntex ? ntex : 1u) : 0.0;
  const double loss_hf = (nflat > 100u) ? accs[6] / (double)(nflat ? nflat : 1u) : 0.0;
  const double loss_ic = (nflat > 100u) ? accs[7] / (double)(nflat ? nflat : 1u) : 0.0;
  const double denfb = (double)(nfb > 0u ? nfb : 1u);
  const double loss_lf = (nfb > 100u) ? accs[8] / denfb : 0.0;
  const double loss_mid = (nfb > 100u) ? accs[9] / denfb : 0.0;
  const double loss_syn = (nfb > 100u) ? accs[10] / denfb : 0.0;

  const double total = 2.0 * loss_rc + 1.5 * loss_hu + 1.0 * loss_edge +
                       0.8 * loss_tex + 1.5 * loss_hf + 0.8 * loss_mid +
                       0.6 * loss_lf + 1.0 * loss_syn + 0.8 * loss_ic;
  out[0] = (float)total;
}

extern "C" void kernel_launch(void* const* d_in, const int* in_sizes, int n_in,
                              void* d_out, int out_size, void* d_ws,
                              size_t ws_size, hipStream_t stream) {
  (void)in_sizes; (void)n_in; (void)out_size;
  const float* y_pred = (const float*)d_in[0];
  const float* noise_pred = (const float*)d_in[1];
  const float* x_i = (const float*)d_in[2];
  // d_in[3] = x_ip1: unused by the reference
  const float* x_mid = (const float*)d_in[4];
  const float* Wt = (const float*)d_in[5];
  const float* nsyn = (const float*)d_in[6];
  float* out = (float*)d_out;

  char* ws = (char*)d_ws;
  double* accs = (double*)ws;                    // 16 doubles @ 0
  unsigned* cnts = (unsigned*)(ws + 128);        // 16 uints @ 128
  unsigned* hist_final = (unsigned*)(ws + 256);  // NCOPY x 2048 uints
  const size_t FIXED = 256 + (size_t)NCOPY * NHIST * 4;  // 65792

  size_t avail = (ws_size > FIXED) ? (ws_size - FIXED) : 0;
  long long cap = (long long)(avail / 4);
  if (cap > (long long)BB * HWSZ) cap = (long long)BB * HWSZ;
  int fb_cap = (int)cap;
  unsigned* fb_list = (unsigned*)(ws + FIXED);

  hipMemsetAsync(ws, 0, FIXED, stream);
  pass1_kernel<<<NBLK1, 256, 0, stream>>>(y_pred, x_i, Wt, accs, cnts,
                                          fb_list, fb_cap, hist_final);
  pass2_kernel<<<512, 256, 0, stream>>>(y_pred, x_i, x_mid, noise_pred, nsyn,
                                        accs, cnts, fb_list, fb_cap);
  finalize_kernel<<<1, 256, 0, stream>>>(accs, cnts, hist_final, out);
}

// Round 4
// 269.465 us; speedup vs baseline: 1.0263x; 1.0263x over previous
//
#include <hip/hip_runtime.h>

// HighQualityNSN2NLoss — B=16, H=W=768, fp32, scalar out. x_ip1 unused.
//
// R7 (stream-shape hypothesis): R3/R5/R6 all plateau at ~1.55 TB/s logical
// regardless of waves (12/24/8) or ILP -> suspect memory-system throughput
// for ~9000 concurrent 1KB-strip streams. This round changes the ACCESS
// PATTERN, not the wave count:
//  - Full-row lanes: lane owns 12 contiguous px (64*12=768). 3x dwordx4 per
//    row per array, sequential multi-KB runs, 3x fewer streams. No mid-row
//    strip edges -> no divergent edge scalar loads; x-neighbors in-lane
//    (2 shfl/row/array only).
//  - XCD-chunked block swizzle: each XCD owns 2 complete images; halo rows
//    (HSEG=6 -> 8/6 reads on yp/xi) hit same-XCD L2.
//  - Depth-1 ping-pong prefetch, ROLLED 2-phase loop (R6 lesson: full unroll
//    -> VGPR 256 + spill. Target <=220 VGPR, watch WRITE_SIZE for spill).
//  - R6 numbers: profiled pass1 192us but bench +7.5us only -> profiled dur
//    inflated at low occupancy; trust bench deltas + R3/R5 profiles.
// Decision rule: if this lands ~85-92us (1.55 TB/s on +10% bytes), the
// ceiling is stream-shape-independent and R3 was already within 4% of it.

#define HH 768
#define WW 768
#define BB 16
#define HWSZ (HH * WW)
#define NPXD ((double)BB * (double)HWSZ)

#define NB 1024
#define NHIST (2 * NB)
#define NCOPY 8            // global hist copies (power of 2)

#define HSEG 6             // rows per wave-job (full width)
#define NSEG (HH / HSEG)   // 128
#define NJOBS (BB * NSEG)  // 2048
#define NBLK1 (NJOBS / 4)  // 512 blocks (4 waves each) = 2/CU

#define FBBUF 192          // per-wave fb buffer (wave covers 4608 px)

__device__ __forceinline__ float wredf(float v) {
#pragma unroll
  for (int o = 32; o > 0; o >>= 1) v += __shfl_down(v, o, 64);
  return v;
}
__device__ __forceinline__ unsigned wredu(unsigned v) {
#pragma unroll
  for (int o = 32; o > 0; o >>= 1) v += __shfl_down(v, o, 64);
  return v;
}

// Raw full row: lane holds px [12*lane .. 12*lane+11] as 3 float4.
struct RawF {
  float4 a, b, c;
};

__device__ __forceinline__ RawF issue_frow(const float* __restrict__ p, int y,
                                           int lane) {
  const float* rp = p + (size_t)y * WW + lane * 12;
  RawF r;
  r.a = *(const float4*)(rp);
  r.b = *(const float4*)(rp + 4);
  r.c = *(const float4*)(rp + 8);
  return r;
}

// Finished row: 12 px + left/right cross-lane neighbors.
struct FRow {
  float f[12];
  float l, r;
};

__device__ __forceinline__ FRow finish_frow(const RawF& rr, bool valid,
                                            int lane) {
  FRow r;
  if (!valid) {  // wave-uniform (row outside image -> zero pad)
#pragma unroll
    for (int i = 0; i < 12; i++) r.f[i] = 0.f;
    r.l = 0.f;
    r.r = 0.f;
    return r;
  }
  r.f[0] = rr.a.x; r.f[1] = rr.a.y; r.f[2] = rr.a.z; r.f[3] = rr.a.w;
  r.f[4] = rr.b.x; r.f[5] = rr.b.y; r.f[6] = rr.b.z; r.f[7] = rr.b.w;
  r.f[8] = rr.c.x; r.f[9] = rr.c.y; r.f[10] = rr.c.z; r.f[11] = rr.c.w;
  const float lf = __shfl_up(rr.c.w, 1, 64);
  const float rt = __shfl_down(rr.a.x, 1, 64);
  r.l = (lane == 0) ? 0.f : lf;    // x = -1 zero pad
  r.r = (lane == 63) ? 0.f : rt;   // x = 768 zero pad
  return r;
}

#define LNB(row, j) ((j) == 0 ? (row).l : (row).f[(j)-1])
#define RNB(row, j) ((j) == 11 ? (row).r : (row).f[(j) + 1])
// compile-time component select from a RawF (j literal -> folds)
#define RF(r, j)                                                            \
  ((j) == 0 ? (r).a.x : (j) == 1 ? (r).a.y : (j) == 2 ? (r).a.z :           \
   (j) == 3 ? (r).a.w : (j) == 4 ? (r).b.x : (j) == 5 ? (r).b.y :           \
   (j) == 6 ? (r).b.z : (j) == 7 ? (r).b.w : (j) == 8 ? (r).c.x :           \
   (j) == 9 ? (r).c.y : (j) == 10 ? (r).c.z : (r).c.w)

// accs: 0 rc, 1 sum_xi_body, 2 sum_yp_body, 3 edge_x, 4 edge_y,
//       5 tex, 6 hf, 7 ic, 8 lf, 9 mid, 10 syn
// cnts: 0 body, 1 tex, 2 flat, 3 fb (append counter)

__device__ __forceinline__ void row_body(
    const FRow& pm1, const FRow& pc, const FRow& pp1, const FRow& im1,
    const FRow& icr, const FRow& ip1, const RawF& wr, int y, size_t base,
    int lane, unsigned long long lmask_lt, float& a_rc, float& a_sxi,
    float& a_syp, float& a_ex, float& a_ey, float& a_tex, float& a_hf,
    float& a_ic, unsigned& c_body, unsigned& c_tex, unsigned& c_flat,
    unsigned& fbn, unsigned* s_hist, unsigned* s_fbw,
    unsigned* __restrict__ cnts, unsigned* __restrict__ fb_list, int fb_cap) {
  const int xg0 = lane * 12;
#pragma unroll
  for (int j = 0; j < 12; j++) {
    const float p00 = LNB(pm1, j), p01 = pm1.f[j], p02 = RNB(pm1, j);
    const float p10 = LNB(pc, j),  p11 = pc.f[j],  p12 = RNB(pc, j);
    const float p20 = LNB(pp1, j), p21 = pp1.f[j], p22 = RNB(pp1, j);
    const float i00 = LNB(im1, j), i01 = im1.f[j], i02 = RNB(im1, j);
    const float i10 = LNB(icr, j), i11 = icr.f[j], i12 = RNB(icr, j);
    const float i20 = LNB(ip1, j), i21 = ip1.f[j], i22 = RNB(ip1, j);

    const float gxp = (p02 - p00) + 2.f * (p12 - p10) + (p22 - p20);
    const float gyp = (p20 - p00) + 2.f * (p21 - p01) + (p22 - p02);
    const float lapp = p01 + p10 + p12 + p21 - 4.f * p11;
    const float gxi_ = (i02 - i00) + 2.f * (i12 - i10) + (i22 - i20);
    const float gyi_ = (i20 - i00) + 2.f * (i21 - i01) + (i22 - i02);
    const float lapi = i01 + i10 + i12 + i21 - 4.f * i11;

    const float yv = p11, xv = i11;
    const float wfj = RF(wr, j);
    a_rc += fabsf(yv * wfj - xv * wfj);

    const bool body = (xv > 0.15f) && (xv < 0.85f);
    if (body) {
      c_body++;
      a_sxi += xv;
      a_syp += yv;
      int bx = (int)(xv * (float)NB);
      bx = bx < 0 ? 0 : (bx > NB - 1 ? NB - 1 : bx);
      int by = (int)(yv * (float)NB);
      by = by < 0 ? 0 : (by > NB - 1 ? NB - 1 : by);
      atomicAdd(&s_hist[bx], 1u);
      atomicAdd(&s_hist[NB + by], 1u);
    }

    a_ex += fabsf(gxp - gxi_);
    a_ey += fabsf(gyp - gyi_);

    const float gmi = sqrtf(gxi_ * gxi_ + gyi_ * gyi_ + 1e-8f);
    const float gmp = sqrtf(gxp * gxp + gyp * gyp + 1e-8f);

    if (gmi > 0.03f && gmi < 0.5f) {
      c_tex++;
      a_tex += fabsf(gmp - gmi);
    }
    const bool flat = gmi < 0.03f;
    if (flat) {
      c_flat++;
      a_hf += fabsf(fabsf(lapp) - 0.3f * fabsf(lapi));
      a_ic += fmaxf(gmp - 2.0f * gmi, 0.f);
    }
    // wave-aggregated append of flat&body pixels
    const bool qual = flat && body;
    const unsigned long long m = __ballot(qual);
    if (m) {
      if (qual) {
        const unsigned p = fbn + (unsigned)__popcll(m & lmask_lt);
        const unsigned gidx = (unsigned)(base + (size_t)y * WW + (xg0 + j));
        if (p < FBBUF) {
          s_fbw[p] = gidx;
        } else {  // overflow fallback (never hit on bench data)
          const unsigned gi = atomicAdd(&cnts[3], 1u);
          if ((int)gi < fb_cap) fb_list[gi] = gidx;
        }
      }
      fbn += (unsigned)__popcll(m);  // wave-uniform
    }
  }
}

__global__ __launch_bounds__(256) void pass1_kernel(
    const float* __restrict__ yp, const float* __restrict__ xi,
    const float* __restrict__ wt, double* __restrict__ accs,
    unsigned* __restrict__ cnts, unsigned* __restrict__ fb_list, int fb_cap,
    unsigned* __restrict__ hist_final) {
  __shared__ unsigned s_hist[NHIST];
  __shared__ unsigned s_fb[4][FBBUF];
  __shared__ float s_redf[4][8];
  __shared__ unsigned s_redc[4][3];

  const int tid = threadIdx.x;
  const int lane = tid & 63;
  const int wv = tid >> 6;
  const unsigned long long lmask_lt = (1ull << lane) - 1ull;

  for (int i = tid; i < NHIST; i += 256) s_hist[i] = 0u;
  __syncthreads();

  // XCD-chunked swizzle: XCD r gets blocks [r*64, r*64+64) worth of work
  // = 2 complete images -> halo rows are same-XCD L2 hits.
  const int sb = ((int)blockIdx.x & 7) * (NBLK1 / 8) + ((int)blockIdx.x >> 3);
  const int job = sb * 4 + wv;
  const int seg = job & (NSEG - 1);
  const int b = job / NSEG;
  const int y0 = seg * HSEG;
  const size_t base = (size_t)b * HWSZ;
  const float* ypb = yp + base;
  const float* xib = xi + base;
  const float* wtb = wt + base;

  float a_rc = 0.f, a_sxi = 0.f, a_syp = 0.f, a_ex = 0.f, a_ey = 0.f;
  float a_tex = 0.f, a_hf = 0.f, a_ic = 0.f;
  unsigned c_body = 0u, c_tex = 0u, c_flat = 0u;
  unsigned fbn = 0u;
  unsigned* s_fbw = s_fb[wv];

  // ---- prologue: 7 row-issues in flight before the first wait ----
  const int ym1 = (y0 > 0) ? y0 - 1 : 0;
  RawF t0 = issue_frow(ypb, ym1, lane);
  RawF t1 = issue_frow(ypb, y0, lane);
  RawF t2 = issue_frow(xib, ym1, lane);
  RawF t3 = issue_frow(xib, y0, lane);
  RawF rpE = issue_frow(ypb, y0 + 1, lane);  // consumed at k=0
  RawF riE = issue_frow(xib, y0 + 1, lane);
  RawF wE = issue_frow(wtb, y0, lane);       // consumed at k=0

  FRow pm1 = finish_frow(t0, y0 > 0, lane);
  FRow pc = finish_frow(t1, true, lane);
  FRow im1 = finish_frow(t2, y0 > 0, lane);
  FRow icr = finish_frow(t3, true, lane);

  RawF rpO, riO, wO;

  for (int k = 0; k < HSEG; k += 2) {
    {  // even row y0+k: consume E-buffers (issued 1 row ago), issue O
      const int y = y0 + k;
      const int yi2 = (y + 2 < HH) ? y + 2 : HH - 1;
      rpO = issue_frow(ypb, yi2, lane);
      riO = issue_frow(xib, yi2, lane);
      const int yw = (k + 1 < HSEG) ? y + 1 : y;
      wO = issue_frow(wtb, yw, lane);
      const FRow pp1 = finish_frow(rpE, true, lane);  // y+1 <= y0+5 valid
      const FRow ip1 = finish_frow(riE, true, lane);
      row_body(pm1, pc, pp1, im1, icr, ip1, wE, y, base, lane, lmask_lt,
               a_rc, a_sxi, a_syp, a_ex, a_ey, a_tex, a_hf, a_ic, c_body,
               c_tex, c_flat, fbn, s_hist, s_fbw, cnts, fb_list, fb_cap);
      pm1 = pc; pc = pp1; im1 = icr; icr = ip1;
    }
    {  // odd row y0+k+1: consume O, issue E
      const int y = y0 + k + 1;
      const int yi2 = (y + 2 < HH) ? y + 2 : HH - 1;
      rpE = issue_frow(ypb, yi2, lane);
      riE = issue_frow(xib, yi2, lane);
      const int yw = (k + 2 < HSEG) ? y + 1 : y;
      wE = issue_frow(wtb, yw, lane);
      const bool v = (y + 1 < HH);  // false only at seg=127 last row
      const FRow pp1 = finish_frow(rpO, v, lane);
      const FRow ip1 = finish_frow(riO, v, lane);
      row_body(pm1, pc, pp1, im1, icr, ip1, wO, y, base, lane, lmask_lt,
               a_rc, a_sxi, a_syp, a_ex, a_ey, a_tex, a_hf, a_ic, c_body,
               c_tex, c_flat, fbn, s_hist, s_fbw, cnts, fb_list, fb_cap);
      pm1 = pc; pc = pp1; im1 = icr; icr = ip1;
    }
  }

  // flush per-wave fb buffer: ONE global atomic per wave
  {
    unsigned n = fbn;
    if (n > FBBUF) n = FBBUF;
    unsigned gbase = 0u;
    if (lane == 0 && n > 0) gbase = atomicAdd(&cnts[3], n);
    gbase = __shfl(gbase, 0, 64);
    for (unsigned i = lane; i < n; i += 64) {
      const unsigned gi = gbase + i;
      if ((int)gi < fb_cap) fb_list[gi] = s_fbw[i];
    }
  }

  __syncthreads();
  // flush block histogram into one of NCOPY global copies (per-bin atomic
  // depth NBLK1/NCOPY = 64; finalize sums the copies)
  {
    const unsigned hco = ((unsigned)blockIdx.x & (NCOPY - 1)) * NHIST;
    for (int i = tid; i < NHIST; i += 256) {
      const unsigned v = s_hist[i];
      if (v) atomicAdd(&hist_final[hco + i], v);
    }
  }

  float f0 = wredf(a_rc), f1 = wredf(a_sxi), f2 = wredf(a_syp);
  float f3 = wredf(a_ex), f4 = wredf(a_ey), f5 = wredf(a_tex);
  float f6 = wredf(a_hf), f7 = wredf(a_ic);
  unsigned u0 = wredu(c_body), u1 = wredu(c_tex), u2 = wredu(c_flat);
  if (lane == 0) {
    s_redf[wv][0] = f0; s_redf[wv][1] = f1; s_redf[wv][2] = f2; s_redf[wv][3] = f3;
    s_redf[wv][4] = f4; s_redf[wv][5] = f5; s_redf[wv][6] = f6; s_redf[wv][7] = f7;
    s_redc[wv][0] = u0; s_redc[wv][1] = u1; s_redc[wv][2] = u2;
  }
  __syncthreads();
  if (tid < 8) {
    double sm = (double)s_redf[0][tid] + (double)s_redf[1][tid] +
                (double)s_redf[2][tid] + (double)s_redf[3][tid];
    atomicAdd(&accs[tid], sm);
  } else if (tid < 11) {
    int k = tid - 8;
    unsigned sm = s_redc[0][k] + s_redc[1][k] + s_redc[2][k] + s_redc[3][k];
    atomicAdd(&cnts[k], sm);
  }
}

__global__ __launch_bounds__(256) void pass2_kernel(
    const float* __restrict__ yp, const float* __restrict__ xi,
    const float* __restrict__ xm, const float* __restrict__ npred,
    const float* __restrict__ nsyn, double* __restrict__ accs,
    const unsigned* __restrict__ cnts, const unsigned* __restrict__ fb_list,
    int fb_cap) {
  __shared__ float w3[19];
  __shared__ float w1[7];
  __shared__ double s_red[4][3];
  const int tid = threadIdx.x;
  const int lane = tid & 63;
  const int wv = tid >> 6;

  if (tid == 0) {
    float tmp[19], s = 0.f;
    for (int i = 0; i < 19; i++) {
      float c = (float)(i - 9) / 3.0f;
      tmp[i] = expf(-0.5f * c * c);
      s += tmp[i];
    }
    for (int i = 0; i < 19; i++) w3[i] = tmp[i] / s;
    float tmp1[7], s1 = 0.f;
    for (int i = 0; i < 7; i++) {
      float c = (float)(i - 3);
      tmp1[i] = expf(-0.5f * c * c);
      s1 += tmp1[i];
    }
    for (int i = 0; i < 7; i++) w1[i] = tmp1[i] / s1;
  }
  __syncthreads();

  unsigned nfb = cnts[3];
  if (nfb > (unsigned)fb_cap) nfb = (unsigned)fb_cap;
  const int wid = (int)((blockIdx.x * blockDim.x + tid) >> 6);
  const int nwaves = (int)((gridDim.x * blockDim.x) >> 6);

  double w_lf = 0.0, w_md = 0.0, w_sy = 0.0;  // lane-0 accumulators

  for (int i = wid; i < (int)nfb; i += nwaves) {
    const unsigned px = fb_list[i];
    const int b = (int)(px / (unsigned)HWSZ);
    const int rem = (int)(px % (unsigned)HWSZ);
    const int y = rem / WW;
    const int x = rem % WW;
    const size_t base = (size_t)b * HWSZ;
    const float* xib = xi + base;
    const float* ypb = yp + base;
    const float* xmb = xm + base;

    float npv = 0.f, nsv = 0.f;
    if (lane == 0) { npv = npred[px]; nsv = nsyn[px]; }

    float s_li = 0.f, s_lp = 0.f, s_lm = 0.f;
    float s_gi = 0.f, s_gp = 0.f;
    const bool interior = (y >= 9) && (y < HH - 9) && (x >= 9) && (x < WW - 9);
    if (interior) {
#pragma unroll
      for (int k = 0; k < 6; k++) {
        const int tap = lane + 64 * k;
        if (tap < 361) {
          const int r = tap / 19, c = tap - r * 19;
          const float wgt = w3[r] * w3[c];
          const int o = (y + r - 9) * WW + (x + c - 9);
          s_li += wgt * xib[o];
          s_lp += wgt * ypb[o];
          s_lm += wgt * xmb[o];
        }
      }
      if (lane < 49) {
        const int r = lane / 7, c = lane - r * 7;
        const float wgt = w1[r] * w1[c];
        const int o = (y + r - 3) * WW + (x + c - 3);
        s_gi = wgt * xib[o];
        s_gp = wgt * ypb[o];
      }
    } else {
#pragma unroll
      for (int k = 0; k < 6; k++) {
        const int tap = lane + 64 * k;
        if (tap < 361) {
          const int r = tap / 19, c = tap - r * 19;
          const int gy = y + r - 9, gx = x + c - 9;
          if (gy >= 0 && gy < HH && gx >= 0 && gx < WW) {
            const float wgt = w3[r] * w3[c];
            const int o = gy * WW + gx;
            s_li += wgt * xib[o];
            s_lp += wgt * ypb[o];
            s_lm += wgt * xmb[o];
          }
        }
      }
      if (lane < 49) {
        const int r = lane / 7, c = lane - r * 7;
        const int gy = y + r - 3, gx = x + c - 3;
        if (gy >= 0 && gy < HH && gx >= 0 && gx < WW) {
          const float wgt = w1[r] * w1[c];
          const int o = gy * WW + gx;
          s_gi = wgt * xib[o];
          s_gp = wgt * ypb[o];
        }
      }
    }
    s_li = wredf(s_li);
    s_lp = wredf(s_lp);
    s_lm = wredf(s_lm);
    s_gi = wredf(s_gi);
    s_gp = wredf(s_gp);
    if (lane == 0) {
      const float lf = fabsf((s_lp - s_lm) - 0.3f * (s_li - s_lm));
      const float mi_ = s_gi - s_li, mp_ = s_gp - s_lp;
      const float md = fabsf(fabsf(mp_) - 0.3f * fabsf(mi_));
      w_lf += (double)lf;
      w_md += (double)md;
      w_sy += (double)fabsf(npv - nsv);
    }
  }

  if (lane == 0) {
    s_red[wv][0] = w_lf; s_red[wv][1] = w_md; s_red[wv][2] = w_sy;
  }
  __syncthreads();
  if (tid < 3) {
    const double t = s_red[0][tid] + s_red[1][tid] + s_red[2][tid] + s_red[3][tid];
    if (t != 0.0) atomicAdd(&accs[8 + tid], t);
  }
}

__global__ __launch_bounds__(256) void finalize_kernel(
    const double* __restrict__ accs, const unsigned* __restrict__ cnts,
    const unsigned* __restrict__ hist, float* __restrict__ out) {
  __shared__ unsigned sc[NHIST];
  __shared__ unsigned wsum[8];
  __shared__ double quant[4];
  const int tid = threadIdx.x;
  const int lane = tid & 63;
  const int wv = tid >> 6;

  if (tid < 4) quant[tid] = 0.0;

#pragma unroll
  for (int h = 0; h < 2; h++) {
    const int baseh = h * NB + tid * 4;
    unsigned v0 = 0u, v1 = 0u, v2 = 0u, v3 = 0u;
#pragma unroll
    for (int c = 0; c < NCOPY; c++) {
      const unsigned* hb = hist + c * NHIST + baseh;
      v0 += hb[0];
      v1 += hb[1];
      v2 += hb[2];
      v3 += hb[3];
    }
    const unsigned s = v0 + v1 + v2 + v3;
    unsigned scl = s;
#pragma unroll
    for (int o = 1; o < 64; o <<= 1) {
      const unsigned t = __shfl_up(scl, o, 64);
      if (lane >= o) scl += t;
    }
    if (lane == 63) wsum[h * 4 + wv] = scl;
    __syncthreads();
    unsigned woff = 0;
    for (int k = 0; k < wv; k++) woff += wsum[h * 4 + k];
    const unsigned excl = woff + scl - s;
    const unsigned c0 = excl + v0;
    const unsigned c1 = c0 + v1;
    const unsigned c2 = c1 + v2;
    const unsigned c3 = c2 + v3;
    sc[baseh + 0] = c0;
    sc[baseh + 1] = c1;
    sc[baseh + 2] = c2;
    sc[baseh + 3] = c3;
    __syncthreads();
  }

  const unsigned nb = cnts[0];
  if (tid < 4 && nb > 4096u) {
    const int h = tid >> 1;
    const double q = (tid & 1) ? 0.75 : 0.25;
    const double pos = q * (double)(nb - 1u);
    int lo = 0, hi = NB - 1;
    while (lo < hi) {
      const int mid = (lo + hi) >> 1;
      if ((double)sc[h * NB + mid] > pos) hi = mid; else lo = mid + 1;
    }
    const unsigned cum_before = (lo > 0) ? sc[h * NB + lo - 1] : 0u;
    const unsigned m = sc[h * NB + lo] - cum_before;
    const double local = pos - (double)cum_before;
    quant[tid] = ((double)lo + (local + 0.5) / (double)(m ? m : 1u)) *
                 (1.0 / (double)NB);
  }
  __syncthreads();
  if (tid != 0) return;

  const unsigned ntex = cnts[1], nflat = cnts[2], nfb = cnts[3];
  const double loss_rc = accs[0] / NPXD;
  const double denb = (double)(nb > 0u ? nb : 1u);
  const double mean_in = accs[1] / denb;
  const double mean_pr = accs[2] / denb;

  double loss_hu = 0.0;
  if (nb > 4096u) {
    const double q25i = quant[0], q75i = quant[1];
    const double q25p = quant[2], q75p = quant[3];
    const double d = mean_pr - mean_in;
    loss_hu = d * d + 0.5 * ((q25p - q25i) * (q25p - q25i) +
                             (q75p - q75i) * (q75p - q75i));
  }

  const double loss_edge = accs[3] / NPXD + accs[4] / NPXD;
  const double loss_tex = (ntex > 100u) ? accs[5] / (double)(ntex ? ntex : 1u) : 0.0;
  const double loss_hf = (nflat > 100u) ? accs[6] / (double)(nflat ? nflat : 1u) : 0.0;
  const double loss_ic = (nflat > 100u) ? accs[7] / (double)(nflat ? nflat : 1u) : 0.0;
  const double denfb = (double)(nfb > 0u ? nfb : 1u);
  const double loss_lf = (nfb > 100u) ? accs[8] / denfb : 0.0;
  const double loss_mid = (nfb > 100u) ? accs[9] / denfb : 0.0;
  const double loss_syn = (nfb > 100u) ? accs[10] / denfb : 0.0;

  const double total = 2.0 * loss_rc + 1.5 * loss_hu + 1.0 * loss_edge +
                       0.8 * loss_tex + 1.5 * loss_hf + 0.8 * loss_mid +
                       0.6 * loss_lf + 1.0 * loss_syn + 0.8 * loss_ic;
  out[0] = (float)total;
}

extern "C" void kernel_launch(void* const* d_in, const int* in_sizes, int n_in,
                              void* d_out, int out_size, void* d_ws,
                              size_t ws_size, hipStream_t stream) {
  (void)in_sizes; (void)n_in; (void)out_size;
  const float* y_pred = (const float*)d_in[0];
  const float* noise_pred = (const float*)d_in[1];
  const float* x_i = (const float*)d_in[2];
  // d_in[3] = x_ip1: unused by the reference
  const float* x_mid = (const float*)d_in[4];
  const float* Wt = (const float*)d_in[5];
  const float* nsyn = (const float*)d_in[6];
  float* out = (float*)d_out;

  char* ws = (char*)d_ws;
  double* accs = (double*)ws;                    // 16 doubles @ 0
  unsigned* cnts = (unsigned*)(ws + 128);        // 16 uints @ 128
  unsigned* hist_final = (unsigned*)(ws + 256);  // NCOPY x 2048 uints
  const size_t FIXED = 256 + (size_t)NCOPY * NHIST * 4;  // 65792

  size_t avail = (ws_size > FIXED) ? (ws_size - FIXED) : 0;
  long long cap = (long long)(avail / 4);
  if (cap > (long long)BB * HWSZ) cap = (long long)BB * HWSZ;
  int fb_cap = (int)cap;
  unsigned* fb_list = (unsigned*)(ws + FIXED);

  hipMemsetAsync(ws, 0, FIXED, stream);
  pass1_kernel<<<NBLK1, 256, 0, stream>>>(y_pred, x_i, Wt, accs, cnts,
                                          fb_list, fb_cap, hist_final);
  pass2_kernel<<<512, 256, 0, stream>>>(y_pred, x_i, x_mid, noise_pred, nsyn,
                                        accs, cnts, fb_list, fb_cap);
  finalize_kernel<<<1, 256, 0, stream>>>(accs, cnts, hist_final, out);
}

// Round 5
// 262.147 us; speedup vs baseline: 1.0550x; 1.0279x over previous
//
#include <hip/hip_runtime.h>

// HighQualityNSN2NLoss — B=16, H=W=768, fp32, scalar out. x_ip1 unused.
//
// R8: EXACT revert to the best-measured kernel (R3, 262.1 us bench,
// pass1 78.6 us). Four structural experiments (R4-R7) established:
//  - pass1 runs at a hard ~1.55-1.6 TB/s logical-byte service rate,
//    invariant to waves/CU (3.4->13), ILP depth, stream shape, and XCD
//    swizzle. R3's 126 MB / 1.6 TB/s = 78.6 us is within 4% of the
//    halo-free floor (113 MB -> ~71 us).
//  - The remaining ~180 us of bench time is a fixed harness/launch floor,
//    identical with 2 or 4 dispatches (R3 vs R4) — not kernel-addressable.
//  - Forcing occupancy via __launch_bounds__ min-waves spills (R4);
//    register-resident prefetch spills or starves occupancy (R6/R7).
// This is the roofline for this problem shape on MI355X.

#define HH 768
#define WW 768
#define BB 16
#define HWSZ (HH * WW)
#define NPXD ((double)BB * (double)HWSZ)

#define NB 1024
#define NHIST (2 * NB)

#define STRIPS 3           // 256-wide column strips
#define HSEG 12            // rows per wave-job
#define NSEG (HH / HSEG)   // 64
#define NJOBS (STRIPS * NSEG * BB)  // 3072
#define NBLK1 (NJOBS / 4)           // 768 blocks (4 waves each) = 3/CU

#define FBBUF 128          // per-wave fb buffer (expected ~3.4 hits/wave)

__device__ __forceinline__ float wredf(float v) {
#pragma unroll
  for (int o = 32; o > 0; o >>= 1) v += __shfl_down(v, o, 64);
  return v;
}
__device__ __forceinline__ unsigned wredu(unsigned v) {
#pragma unroll
  for (int o = 32; o > 0; o >>= 1) v += __shfl_down(v, o, 64);
  return v;
}

struct Row {
  float f[4];
  float l, r;
};

__device__ __forceinline__ Row load_row(const float* __restrict__ p, int y,
                                        int xl, int x0, int lane) {
  Row r;
  if (y < 0 || y >= HH) {
    r.f[0] = r.f[1] = r.f[2] = r.f[3] = 0.f;
    r.l = 0.f;
    r.r = 0.f;
    return r;
  }
  const float4 v = *(const float4*)(p + (size_t)y * WW + xl);
  r.f[0] = v.x; r.f[1] = v.y; r.f[2] = v.z; r.f[3] = v.w;
  float left = __shfl_up(v.w, 1, 64);
  float right = __shfl_down(v.x, 1, 64);
  if (lane == 0) left = (x0 > 0) ? p[(size_t)y * WW + x0 - 1] : 0.f;
  if (lane == 63) right = (x0 + 256 < WW) ? p[(size_t)y * WW + x0 + 256] : 0.f;
  r.l = left;
  r.r = right;
  return r;
}

#define LNB(row, j) ((j) == 0 ? (row).l : (row).f[(j)-1])
#define RNB(row, j) ((j) == 3 ? (row).r : (row).f[(j) + 1])

// accs: 0 rc, 1 sum_xi_body, 2 sum_yp_body, 3 edge_x, 4 edge_y,
//       5 tex, 6 hf, 7 ic, 8 lf, 9 mid, 10 syn
// cnts: 0 body, 1 tex, 2 flat, 3 fb (append counter)

__global__ __launch_bounds__(256) void pass1_kernel(
    const float* __restrict__ yp, const float* __restrict__ xi,
    const float* __restrict__ wt, double* __restrict__ accs,
    unsigned* __restrict__ cnts, unsigned* __restrict__ fb_list, int fb_cap,
    unsigned* __restrict__ hist_final) {
  __shared__ unsigned s_hist[NHIST];
  __shared__ unsigned s_fb[4][FBBUF];
  __shared__ unsigned s_fbn[4];
  __shared__ float s_redf[4][8];
  __shared__ unsigned s_redc[4][3];

  const int tid = threadIdx.x;
  const int lane = tid & 63;
  const int wv = tid >> 6;
  const unsigned long long lmask_lt = (1ull << lane) - 1ull;

  for (int i = tid; i < NHIST; i += 256) s_hist[i] = 0u;
  if (lane == 0) s_fbn[wv] = 0u;
  __syncthreads();

  const int job = blockIdx.x * 4 + wv;
  const int s = job % STRIPS;
  const int seg = (job / STRIPS) % NSEG;
  const int b = job / (STRIPS * NSEG);
  const int x0 = s * 256;
  const int y0 = seg * HSEG;
  const int xl = x0 + lane * 4;
  const size_t base = (size_t)b * HWSZ;
  const float* ypb = yp + base;
  const float* xib = xi + base;
  const float* wtb = wt + base;

  float a_rc = 0.f, a_sxi = 0.f, a_syp = 0.f, a_ex = 0.f, a_ey = 0.f;
  float a_tex = 0.f, a_hf = 0.f, a_ic = 0.f;
  unsigned c_body = 0u, c_tex = 0u, c_flat = 0u;

  Row pm1 = load_row(ypb, y0 - 1, xl, x0, lane);
  Row pc = load_row(ypb, y0, xl, x0, lane);
  Row im1 = load_row(xib, y0 - 1, xl, x0, lane);
  Row icr = load_row(xib, y0, xl, x0, lane);

  for (int y = y0; y < y0 + HSEG; y++) {
    const Row pp1 = load_row(ypb, y + 1, xl, x0, lane);
    const Row ip1 = load_row(xib, y + 1, xl, x0, lane);
    const float4 w4 = *(const float4*)(wtb + (size_t)y * WW + xl);
    const float wf[4] = {w4.x, w4.y, w4.z, w4.w};

#pragma unroll
    for (int j = 0; j < 4; j++) {
      const float p00 = LNB(pm1, j), p01 = pm1.f[j], p02 = RNB(pm1, j);
      const float p10 = LNB(pc, j),  p11 = pc.f[j],  p12 = RNB(pc, j);
      const float p20 = LNB(pp1, j), p21 = pp1.f[j], p22 = RNB(pp1, j);
      const float i00 = LNB(im1, j), i01 = im1.f[j], i02 = RNB(im1, j);
      const float i10 = LNB(icr, j), i11 = icr.f[j], i12 = RNB(icr, j);
      const float i20 = LNB(ip1, j), i21 = ip1.f[j], i22 = RNB(ip1, j);

      const float gxp = (p02 - p00) + 2.f * (p12 - p10) + (p22 - p20);
      const float gyp = (p20 - p00) + 2.f * (p21 - p01) + (p22 - p02);
      const float lapp = p01 + p10 + p12 + p21 - 4.f * p11;
      const float gxi_ = (i02 - i00) + 2.f * (i12 - i10) + (i22 - i20);
      const float gyi_ = (i20 - i00) + 2.f * (i21 - i01) + (i22 - i02);
      const float lapi = i01 + i10 + i12 + i21 - 4.f * i11;

      const float yv = p11, xv = i11;
      a_rc += fabsf(yv * wf[j] - xv * wf[j]);

      const bool body = (xv > 0.15f) && (xv < 0.85f);
      if (body) {
        c_body++;
        a_sxi += xv;
        a_syp += yv;
        int bx = (int)(xv * (float)NB);
        bx = bx < 0 ? 0 : (bx > NB - 1 ? NB - 1 : bx);
        int by = (int)(yv * (float)NB);
        by = by < 0 ? 0 : (by > NB - 1 ? NB - 1 : by);
        atomicAdd(&s_hist[bx], 1u);
        atomicAdd(&s_hist[NB + by], 1u);
      }

      a_ex += fabsf(gxp - gxi_);
      a_ey += fabsf(gyp - gyi_);

      const float gmi = sqrtf(gxi_ * gxi_ + gyi_ * gyi_ + 1e-8f);
      const float gmp = sqrtf(gxp * gxp + gyp * gyp + 1e-8f);

      if (gmi > 0.03f && gmi < 0.5f) {
        c_tex++;
        a_tex += fabsf(gmp - gmi);
      }
      const bool flat = gmi < 0.03f;
      if (flat) {
        c_flat++;
        a_hf += fabsf(fabsf(lapp) - 0.3f * fabsf(lapi));
        a_ic += fmaxf(gmp - 2.0f * gmi, 0.f);
      }
      // wave-aggregated append of flat&body pixels
      const bool qual = flat && body;
      const unsigned long long m = __ballot(qual);
      if (m) {
        const unsigned bofs = s_fbn[wv];
        if (qual) {
          const unsigned p = bofs + (unsigned)__popcll(m & lmask_lt);
          const unsigned gidx = (unsigned)(base + (size_t)y * WW + (xl + j));
          if (p < FBBUF) {
            s_fb[wv][p] = gidx;
          } else {  // overflow fallback (never hit on bench data)
            const unsigned gi = atomicAdd(&cnts[3], 1u);
            if ((int)gi < fb_cap) fb_list[gi] = gidx;
          }
        }
        s_fbn[wv] = bofs + (unsigned)__popcll(m);  // all lanes, same value
      }
    }
    pm1 = pc; pc = pp1;
    im1 = icr; icr = ip1;
  }

  // flush per-wave fb buffer: ONE global atomic per wave
  {
    unsigned n = s_fbn[wv];
    if (n > FBBUF) n = FBBUF;
    unsigned gbase = 0u;
    if (lane == 0 && n > 0) gbase = atomicAdd(&cnts[3], n);
    gbase = __shfl(gbase, 0, 64);
    for (unsigned i = lane; i < n; i += 64) {
      const unsigned gi = gbase + i;
      if ((int)gi < fb_cap) fb_list[gi] = s_fb[wv][i];
    }
  }

  __syncthreads();
  // flush block histogram straight into the global one (bins spread across
  // channels; ~768 adds per bin total, overlapped with other blocks' work)
  for (int i = tid; i < NHIST; i += 256) {
    const unsigned v = s_hist[i];
    if (v) atomicAdd(&hist_final[i], v);
  }

  float f0 = wredf(a_rc), f1 = wredf(a_sxi), f2 = wredf(a_syp);
  float f3 = wredf(a_ex), f4 = wredf(a_ey), f5 = wredf(a_tex);
  float f6 = wredf(a_hf), f7 = wredf(a_ic);
  unsigned u0 = wredu(c_body), u1 = wredu(c_tex), u2 = wredu(c_flat);
  if (lane == 0) {
    s_redf[wv][0] = f0; s_redf[wv][1] = f1; s_redf[wv][2] = f2; s_redf[wv][3] = f3;
    s_redf[wv][4] = f4; s_redf[wv][5] = f5; s_redf[wv][6] = f6; s_redf[wv][7] = f7;
    s_redc[wv][0] = u0; s_redc[wv][1] = u1; s_redc[wv][2] = u2;
  }
  __syncthreads();
  if (tid < 8) {
    double sm = (double)s_redf[0][tid] + (double)s_redf[1][tid] +
                (double)s_redf[2][tid] + (double)s_redf[3][tid];
    atomicAdd(&accs[tid], sm);
  } else if (tid < 11) {
    int k = tid - 8;
    unsigned sm = s_redc[0][k] + s_redc[1][k] + s_redc[2][k] + s_redc[3][k];
    atomicAdd(&cnts[k], sm);
  }
}

__global__ __launch_bounds__(256) void pass2_kernel(
    const float* __restrict__ yp, const float* __restrict__ xi,
    const float* __restrict__ xm, const float* __restrict__ npred,
    const float* __restrict__ nsyn, double* __restrict__ accs,
    const unsigned* __restrict__ cnts, const unsigned* __restrict__ fb_list,
    int fb_cap) {
  __shared__ float w3[19];
  __shared__ float w1[7];
  __shared__ double s_red[4][3];
  const int tid = threadIdx.x;
  const int lane = tid & 63;
  const int wv = tid >> 6;

  if (tid == 0) {
    float tmp[19], s = 0.f;
    for (int i = 0; i < 19; i++) {
      float c = (float)(i - 9) / 3.0f;
      tmp[i] = expf(-0.5f * c * c);
      s += tmp[i];
    }
    for (int i = 0; i < 19; i++) w3[i] = tmp[i] / s;
    float tmp1[7], s1 = 0.f;
    for (int i = 0; i < 7; i++) {
      float c = (float)(i - 3);
      tmp1[i] = expf(-0.5f * c * c);
      s1 += tmp1[i];
    }
    for (int i = 0; i < 7; i++) w1[i] = tmp1[i] / s1;
  }
  __syncthreads();

  unsigned nfb = cnts[3];
  if (nfb > (unsigned)fb_cap) nfb = (unsigned)fb_cap;
  const int wid = (int)((blockIdx.x * blockDim.x + tid) >> 6);
  const int nwaves = (int)((gridDim.x * blockDim.x) >> 6);

  double w_lf = 0.0, w_md = 0.0, w_sy = 0.0;  // lane-0 accumulators

  for (int i = wid; i < (int)nfb; i += nwaves) {
    const unsigned px = fb_list[i];
    const int b = (int)(px / (unsigned)HWSZ);
    const int rem = (int)(px % (unsigned)HWSZ);
    const int y = rem / WW;
    const int x = rem % WW;
    const size_t base = (size_t)b * HWSZ;
    const float* xib = xi + base;
    const float* ypb = yp + base;
    const float* xmb = xm + base;

    float npv = 0.f, nsv = 0.f;
    if (lane == 0) { npv = npred[px]; nsv = nsyn[px]; }

    float s_li = 0.f, s_lp = 0.f, s_lm = 0.f;
    float s_gi = 0.f, s_gp = 0.f;
    const bool interior = (y >= 9) && (y < HH - 9) && (x >= 9) && (x < WW - 9);
    if (interior) {
#pragma unroll
      for (int k = 0; k < 6; k++) {
        const int tap = lane + 64 * k;
        if (tap < 361) {
          const int r = tap / 19, c = tap - r * 19;
          const float wgt = w3[r] * w3[c];
          const int o = (y + r - 9) * WW + (x + c - 9);
          s_li += wgt * xib[o];
          s_lp += wgt * ypb[o];
          s_lm += wgt * xmb[o];
        }
      }
      if (lane < 49) {
        const int r = lane / 7, c = lane - r * 7;
        const float wgt = w1[r] * w1[c];
        const int o = (y + r - 3) * WW + (x + c - 3);
        s_gi = wgt * xib[o];
        s_gp = wgt * ypb[o];
      }
    } else {
#pragma unroll
      for (int k = 0; k < 6; k++) {
        const int tap = lane + 64 * k;
        if (tap < 361) {
          const int r = tap / 19, c = tap - r * 19;
          const int gy = y + r - 9, gx = x + c - 9;
          if (gy >= 0 && gy < HH && gx >= 0 && gx < WW) {
            const float wgt = w3[r] * w3[c];
            const int o = gy * WW + gx;
            s_li += wgt * xib[o];
            s_lp += wgt * ypb[o];
            s_lm += wgt * xmb[o];
          }
        }
      }
      if (lane < 49) {
        const int r = lane / 7, c = lane - r * 7;
        const int gy = y + r - 3, gx = x + c - 3;
        if (gy >= 0 && gy < HH && gx >= 0 && gx < WW) {
          const float wgt = w1[r] * w1[c];
          const int o = gy * WW + gx;
          s_gi = wgt * xib[o];
          s_gp = wgt * ypb[o];
        }
      }
    }
    s_li = wredf(s_li);
    s_lp = wredf(s_lp);
    s_lm = wredf(s_lm);
    s_gi = wredf(s_gi);
    s_gp = wredf(s_gp);
    if (lane == 0) {
      const float lf = fabsf((s_lp - s_lm) - 0.3f * (s_li - s_lm));
      const float mi_ = s_gi - s_li, mp_ = s_gp - s_lp;
      const float md = fabsf(fabsf(mp_) - 0.3f * fabsf(mi_));
      w_lf += (double)lf;
      w_md += (double)md;
      w_sy += (double)fabsf(npv - nsv);
    }
  }

  if (lane == 0) {
    s_red[wv][0] = w_lf; s_red[wv][1] = w_md; s_red[wv][2] = w_sy;
  }
  __syncthreads();
  if (tid < 3) {
    const double t = s_red[0][tid] + s_red[1][tid] + s_red[2][tid] + s_red[3][tid];
    if (t != 0.0) atomicAdd(&accs[8 + tid], t);
  }
}

__global__ __launch_bounds__(256) void finalize_kernel(
    const double* __restrict__ accs, const unsigned* __restrict__ cnts,
    const unsigned* __restrict__ hist, float* __restrict__ out) {
  __shared__ unsigned sc[NHIST];
  __shared__ unsigned wsum[8];
  __shared__ double quant[4];
  const int tid = threadIdx.x;
  const int lane = tid & 63;
  const int wv = tid >> 6;

  if (tid < 4) quant[tid] = 0.0;

#pragma unroll
  for (int h = 0; h < 2; h++) {
    const int baseh = h * NB + tid * 4;
    const unsigned v0 = hist[baseh + 0];
    const unsigned v1 = hist[baseh + 1];
    const unsigned v2 = hist[baseh + 2];
    const unsigned v3 = hist[baseh + 3];
    const unsigned s = v0 + v1 + v2 + v3;
    unsigned scl = s;
#pragma unroll
    for (int o = 1; o < 64; o <<= 1) {
      const unsigned t = __shfl_up(scl, o, 64);
      if (lane >= o) scl += t;
    }
    if (lane == 63) wsum[h * 4 + wv] = scl;
    __syncthreads();
    unsigned woff = 0;
    for (int k = 0; k < wv; k++) woff += wsum[h * 4 + k];
    const unsigned excl = woff + scl - s;
    const unsigned c0 = excl + v0;
    const unsigned c1 = c0 + v1;
    const unsigned c2 = c1 + v2;
    const unsigned c3 = c2 + v3;
    sc[baseh + 0] = c0;
    sc[baseh + 1] = c1;
    sc[baseh + 2] = c2;
    sc[baseh + 3] = c3;
    __syncthreads();
  }

  const unsigned nb = cnts[0];
  if (tid < 4 && nb > 4096u) {
    const int h = tid >> 1;
    const double q = (tid & 1) ? 0.75 : 0.25;
    const double pos = q * (double)(nb - 1u);
    int lo = 0, hi = NB - 1;
    while (lo < hi) {
      const int mid = (lo + hi) >> 1;
      if ((double)sc[h * NB + mid] > pos) hi = mid; else lo = mid + 1;
    }
    const unsigned cum_before = (lo > 0) ? sc[h * NB + lo - 1] : 0u;
    const unsigned m = sc[h * NB + lo] - cum_before;
    const double local = pos - (double)cum_before;
    quant[tid] = ((double)lo + (local + 0.5) / (double)(m ? m : 1u)) *
                 (1.0 / (double)NB);
  }
  __syncthreads();
  if (tid != 0) return;

  const unsigned ntex = cnts[1], nflat = cnts[2], nfb = cnts[3];
  const double loss_rc = accs[0] / NPXD;
  const double denb = (double)(nb > 0u ? nb : 1u);
  const double mean_in = accs[1] / denb;
  const double mean_pr = accs[2] / denb;

  double loss_hu = 0.0;
  if (nb > 4096u) {
    const double q25i = quant[0], q75i = quant[1];
    const double q25p = quant[2], q75p = quant[3];
    const double d = mean_pr - mean_in;
    loss_hu = d * d + 0.5 * ((q25p - q25i) * (q25p - q25i) +
                             (q75p - q75i) * (q75p - q75i));
  }

  const double loss_edge = accs[3] / NPXD + accs[4] / NPXD;
  const double loss_tex = (ntex > 100u) ? accs[5] / (double)(ntex ? ntex : 1u) : 0.0;
  const double loss_hf = (nflat > 100u) ? accs[6] / (double)(nflat ? nflat : 1u) : 0.0;
  const double loss_ic = (nflat > 100u) ? accs[7] / (double)(nflat ? nflat : 1u) : 0.0;
  const double denfb = (double)(nfb > 0u ? nfb : 1u);
  const double loss_lf = (nfb > 100u) ? accs[8] / denfb : 0.0;
  const double loss_mid = (nfb > 100u) ? accs[9] / denfb : 0.0;
  const double loss_syn = (nfb > 100u) ? accs[10] / denfb : 0.0;

  const double total = 2.0 * loss_rc + 1.5 * loss_hu + 1.0 * loss_edge +
                       0.8 * loss_tex + 1.5 * loss_hf + 0.8 * loss_mid +
                       0.6 * loss_lf + 1.0 * loss_syn + 0.8 * loss_ic;
  out[0] = (float)total;
}

extern "C" void kernel_launch(void* const* d_in, const int* in_sizes, int n_in,
                              void* d_out, int out_size, void* d_ws,
                              size_t ws_size, hipStream_t stream) {
  (void)in_sizes; (void)n_in; (void)out_size;
  const float* y_pred = (const float*)d_in[0];
  const float* noise_pred = (const float*)d_in[1];
  const float* x_i = (const float*)d_in[2];
  // d_in[3] = x_ip1: unused by the reference
  const float* x_mid = (const float*)d_in[4];
  const float* Wt = (const float*)d_in[5];
  const float* nsyn = (const float*)d_in[6];
  float* out = (float*)d_out;

  char* ws = (char*)d_ws;
  double* accs = (double*)ws;                    // 16 doubles
  unsigned* cnts = (unsigned*)(ws + 128);        // 16 uints
  unsigned* hist_final = (unsigned*)(ws + 256);  // 2048 uints
  const size_t FIXED = 16384;

  size_t avail = (ws_size > FIXED) ? (ws_size - FIXED) : 0;
  long long cap = (long long)(avail / 4);
  if (cap > (long long)BB * HWSZ) cap = (long long)BB * HWSZ;
  int fb_cap = (int)cap;
  unsigned* fb_list = (unsigned*)(ws + FIXED);

  hipMemsetAsync(ws, 0, FIXED, stream);
  pass1_kernel<<<NBLK1, 256, 0, stream>>>(y_pred, x_i, Wt, accs, cnts,
                                          fb_list, fb_cap, hist_final);
  pass2_kernel<<<256, 256, 0, stream>>>(y_pred, x_i, x_mid, noise_pred, nsyn,
                                        accs, cnts, fb_list, fb_cap);
  finalize_kernel<<<1, 256, 0, stream>>>(accs, cnts, hist_final, out);
}